// Round 5
// baseline (29.205 us; speedup 1.0000x reference)
//
#include <hip/hip_runtime.h>

// out[b,i] = sum_j A[z_b][i][j] * x[b,j]  -  dt * x[b,i]^3
// A[m] = dt*beta_m*W_m + diag(1 + dt*(mu_m + alpha_m*deg_m))
// W_m = sigmoid(0.5*(G_m + G_m^T)) with zero diagonal; deg_m = row-sum of W_m.
//
// Structure: one item per thread, maximal grid (no grid-stride loop). The
// X/z loads are issued BEFORE the A-matrix prologue so the 16-lane expf
// chain + barrier hide under global-load latency. HW block scheduler
// backfills CUs continuously -> sustained occupancy without a drain tail.

typedef float fvec4 __attribute__((ext_vector_type(4)));

__global__ __launch_bounds__(256) void bistable_kernel(
    const float* __restrict__ X,          // (B,4)
    const int*   __restrict__ z,          // (B,)
    const float* __restrict__ dt_val,     // (1,)
    const float* __restrict__ G,          // (4,4,4)
    const float* __restrict__ mu_logits,  // (4,4)
    const float* __restrict__ alpha_p,    // (4,)
    const float* __restrict__ beta_p,     // (4,)
    float* __restrict__ out,              // (B,4)
    int Bn)
{
    __shared__ float A[4 * 16];

    const int t = threadIdx.x;
    const int idx = blockIdx.x * 256 + t;

    // Issue the streaming loads FIRST (independent of the prologue).
    fvec4 xv;
    int m = 0;
    const bool valid = (idx < Bn);
    if (valid) {
        xv = ((const fvec4*)X)[idx];
        m = z[idx];
    }
    const float dt = dt_val[0];

    if (t < 16) {
        const int mm = t >> 2;     // mode
        const int i  = t & 3;      // row
        float w[4];
        float deg = 0.0f;
        #pragma unroll
        for (int j = 0; j < 4; ++j) {
            float s = 0.5f * (G[mm * 16 + i * 4 + j] + G[mm * 16 + j * 4 + i]);
            float wv = 1.0f / (1.0f + __expf(-s));
            if (j == i) wv = 0.0f;   // zero diagonal
            w[j] = wv;
            deg += wv;
        }
        const float mu = 0.1f + 1.4f / (1.0f + __expf(-mu_logits[mm * 4 + i]));
        const float a = alpha_p[mm];
        const float b = beta_p[mm];
        float arow[4];
        #pragma unroll
        for (int j = 0; j < 4; ++j) arow[j] = dt * b * w[j];
        arow[i] = 1.0f + dt * (mu + a * deg);   // fold diag (W diag is 0)
        #pragma unroll
        for (int j = 0; j < 4; ++j) A[mm * 16 + i * 4 + j] = arow[j];
    }
    __syncthreads();

    if (!valid) return;

    const float* __restrict__ a = &A[m * 16];
    const float x0 = xv.x, x1 = xv.y, x2 = xv.z, x3 = xv.w;
    fvec4 ov;
    ov.x = a[0]  * x0 + a[1]  * x1 + a[2]  * x2 + a[3]  * x3 - dt * x0 * x0 * x0;
    ov.y = a[4]  * x0 + a[5]  * x1 + a[6]  * x2 + a[7]  * x3 - dt * x1 * x1 * x1;
    ov.z = a[8]  * x0 + a[9]  * x1 + a[10] * x2 + a[11] * x3 - dt * x2 * x2 * x2;
    ov.w = a[12] * x0 + a[13] * x1 + a[14] * x2 + a[15] * x3 - dt * x3 * x3 * x3;

    __builtin_nontemporal_store(ov, &((fvec4*)out)[idx]);
}

extern "C" void kernel_launch(void* const* d_in, const int* in_sizes, int n_in,
                              void* d_out, int out_size, void* d_ws, size_t ws_size,
                              hipStream_t stream) {
    const float* X         = (const float*)d_in[0];
    const int*   z         = (const int*)d_in[1];
    const float* dt_val    = (const float*)d_in[2];
    const float* G         = (const float*)d_in[3];
    const float* mu_logits = (const float*)d_in[4];
    const float* alpha_p   = (const float*)d_in[5];
    const float* beta_p    = (const float*)d_in[6];
    float* out = (float*)d_out;

    const int Bn = in_sizes[1];   // number of items (z count)

    const int block = 256;
    const int grid = (Bn + block - 1) / block;   // 16384 blocks: 1 item/thread

    bistable_kernel<<<grid, block, 0, stream>>>(X, z, dt_val, G, mu_logits,
                                                alpha_p, beta_p, out, Bn);
}